// Round 6
// baseline (165.282 us; speedup 1.0000x reference)
//
#include <hip/hip_runtime.h>
#include <hip/hip_bf16.h>

#define B_     4
#define V_IN   12500
#define V_OUT  50000
#define C_IN   64
#define C_OUT  32
#define SPIRAL 9
#define K_NNZ  3
#define ROWS   (B_ * V_OUT)       // 200000
#define KDIM   (SPIRAL * C_IN)    // 576
#define KSTEPS (KDIM / 32)        // 18 (16x16x32 MFMA)
#define WFRAG_ELEMS (KSTEPS * 2 * 64 * 8)  // 18432 bf16 = 36864 B

#define GROUPS_PER_B (V_OUT / 16) // 3125 16-row groups per batch (k1)
#define G1           2048         // k1 blocks (+1 W-prep); 256 per XCD
#define TILES_PER_B  782          // 781 full 64-row tiles + one 16-row tail (k2)
#define G2           512          // k2: 64 blocks per (b,ch) XCD; 2 blocks/CU (72KB LDS)
#define TSTEP        64           // tiles stride = blocks per partition
#define G3           2048         // combine blocks

#define SLOTB        1024         // bytes per gather slot (64 lanes * 16 B)
#define BUFB         (SPIRAL * SLOTB)      // 9216 B per wave per buffer

typedef __attribute__((ext_vector_type(8))) short short8_t;      // 8 bf16 (4 VGPRs)
typedef __attribute__((ext_vector_type(4))) float floatx4;       // 4 fp32 acc
typedef __attribute__((ext_vector_type(4))) unsigned short u16x4;

__device__ __forceinline__ unsigned short f32_to_bf16(float f) {
    unsigned int u = __float_as_uint(f);
    unsigned int r = u + 0x7fffu + ((u >> 16) & 1u);   // round-to-nearest-even
    return (unsigned short)(r >> 16);
}

// Async global->LDS, 16B per lane. LDS dest = base + lane*16 (linear, HW rule).
__device__ __forceinline__ void glds16(const void* g, void* l) {
    __builtin_amdgcn_global_load_lds(
        (const __attribute__((address_space(1))) unsigned int*)g,
        (__attribute__((address_space(3))) unsigned int*)l, 16, 0, 0);
}

// Kernel 1: up[b,v,c] = sum_k x[b,up_idx[v,k],c]*up_val[v,k] -> bf16,
// stored as TWO channel planes: plane[ch][b][v][32], ch = c>>5.
// Each plane per batch = 50000*64B = 3.2 MB -> fits one XCD's 4 MB L2 in k2.
// (R2 verified: gemm FETCH_SIZE 170 MB -> 19.8 MB with this layout.)
// Block G1: rearrange weight (576x32 fp32) into MFMA fragment order (bf16).
__global__ __launch_bounds__(256) void upsample_kernel(
    const float* __restrict__ x,
    const int* __restrict__ up_idx,
    const float* __restrict__ up_val,
    const float* __restrict__ weight,
    unsigned short* __restrict__ up_planes,
    unsigned short* __restrict__ w_frag)
{
    int tid = threadIdx.x;
    if (blockIdx.x == G1) {
        for (int idx = tid; idx < WFRAG_ELEMS; idx += 256) {
            int j     = idx & 7;
            int lane  = (idx >> 3) & 63;
            int ntile = (idx >> 9) & 1;
            int kstep = idx >> 10;
            int k = kstep * 32 + (lane >> 4) * 8 + j;
            int n = ntile * 16 + (lane & 15);
            w_frag[idx] = f32_to_bf16(weight[k * C_OUT + n]);
        }
        return;
    }
    int xcd = blockIdx.x & 7;
    int b   = xcd >> 1;                     // batch owned by this XCD pair
    int h   = xcd & 1;
    int j   = blockIdx.x >> 3;              // [0, 256)
    int lane16 = tid & 15;                  // 4 channels each
    int sub    = tid >> 4;                  // row within 16-row group
    int half   = lane16 >> 3;               // channel plane (c>=32)
    int c8     = lane16 & 7;                // 4-short chunk within plane row

    const float* xb = x + (size_t)b * V_IN * C_IN;
    unsigned short* plane = up_planes
        + ((size_t)(half * B_ + b)) * V_OUT * 32 + (size_t)c8 * 4;

    for (int gl = h + 2 * j; gl < GROUPS_PER_B; gl += 512) {
        int v = gl * 16 + sub;              // local row within batch b
        const int*   ui = up_idx + v * K_NNZ;
        const float* uv = up_val + v * K_NNZ;
        float a0 = 0.f, a1 = 0.f, a2 = 0.f, a3 = 0.f;
#pragma unroll
        for (int k = 0; k < K_NNZ; k++) {
            int u = __builtin_nontemporal_load(ui + k);
            float val = __builtin_nontemporal_load(uv + k);
            const float4* xp = (const float4*)(xb + (size_t)u * C_IN) + lane16;
            float4 xv = *xp;
            a0 += val * xv.x; a1 += val * xv.y; a2 += val * xv.z; a3 += val * xv.w;
        }
        u16x4 o;
        o[0] = f32_to_bf16(a0); o[1] = f32_to_bf16(a1);
        o[2] = f32_to_bf16(a2); o[3] = f32_to_bf16(a3);
        __builtin_nontemporal_store(o, (u16x4*)(plane + (size_t)v * 32));
    }
}

// Kernel 2: partial GEMM over one K-half. XCD xcd = b*2+ch.
// R6: PIPELINED transposed gather (R5's coalesced global_load_lds + 1-deep
// double buffer with counted vmcnt(9)). Per iteration:
//   idx(t+2)[nt] -> glds(t+1 -> buf^1) -> vmcnt(9) -> compute(t from buf).
// vmcnt(9) retires everything older than the 9 just-issued gathers (i.e.
// exactly tile t's gathers + idx loads + stores) while t+1's 9 stay in
// flight -- count is robust to how the compiler splits the idx loads.
// Spiral idx loads are nontemporal: 1.8 MB/XCD of zero-reuse stream must
// not evict the 3.2 MB resident plane (3.2+1.8 > 4 MB L2).
__global__ __launch_bounds__(256, 2) void gemm_half_kernel(
    const unsigned short* __restrict__ up_planes,
    const int* __restrict__ spiral,
    const unsigned short* __restrict__ w_frag,
    float* __restrict__ p0,
    float* __restrict__ out)
{
    __shared__ unsigned short gbuf[4 * 2 * SPIRAL * 512];   // 4 waves * 2 bufs * 9 KB

    int tid  = threadIdx.x;
    int wave = tid >> 6;
    int lane = tid & 63;
    int m    = lane & 15;
    int quad = lane >> 4;
    int r    = lane >> 2;          // gather row within 16-row wave tile
    int q    = lane & 3;           // gather sector lane
    int swz  = q ^ ((r >> 1) & 3); // sector actually fetched by this lane
    int fm   = (m >> 1) & 3;       // read-side swizzle for row m

    int xcd = blockIdx.x & 7;
    int b   = xcd >> 1;
    int ch  = xcd & 1;
    int j   = blockIdx.x >> 3;              // [0, TSTEP)

    // W fragments for this half -> registers (loop-invariant, 72 VGPR).
    short8_t w[2 * SPIRAL];
#pragma unroll
    for (int f = 0; f < 2 * SPIRAL; f++) {
        int s  = f >> 1;
        int nt = f & 1;
        w[f] = *(const short8_t*)(w_frag + (((size_t)(2 * s + ch) * 2 + nt) * 64 + lane) * 8);
    }

    const unsigned short* upb = up_planes + ((size_t)(ch * B_ + b)) * V_OUT * 32;
    float* dst = (ch ? out : p0) + (size_t)b * V_OUT * C_OUT;
    char* mybuf = (char*)gbuf + (size_t)wave * 2 * BUFB;

    // ---- prologue: idx(j), idx(j+T), glds(j -> buf0) ----
    int spv[SPIRAL], nspv[SPIRAL];
    {
        int v0 = j * 64 + wave * 16 + r;
        v0 = v0 < V_OUT ? v0 : 0;
        const int* p = spiral + (size_t)v0 * SPIRAL;
#pragma unroll
        for (int s = 0; s < SPIRAL; s++) spv[s] = __builtin_nontemporal_load(p + s);
        int v1 = (j + TSTEP) * 64 + wave * 16 + r;
        v1 = v1 < V_OUT ? v1 : 0;
        const int* pn = spiral + (size_t)v1 * SPIRAL;
#pragma unroll
        for (int s = 0; s < SPIRAL; s++) nspv[s] = __builtin_nontemporal_load(pn + s);
        __builtin_amdgcn_sched_barrier(0);
#pragma unroll
        for (int s = 0; s < SPIRAL; s++) {
            const void* ga = (const char*)upb + (size_t)spv[s] * 64 + swz * 16;
            glds16(ga, mybuf + s * SLOTB);
        }
        __builtin_amdgcn_sched_barrier(0);
#pragma unroll
        for (int s = 0; s < SPIRAL; s++) spv[s] = nspv[s];
    }

    int p = 0;
    for (int tl = j; tl < TILES_PER_B; tl += TSTEP) {
        // 1) idx loads for tile tl+2T (clamped; nontemporal).
        int v2 = (tl + 2 * TSTEP) * 64 + wave * 16 + r;
        v2 = (v2 < V_OUT) ? v2 : 0;
        const int* pn = spiral + (size_t)v2 * SPIRAL;
#pragma unroll
        for (int s = 0; s < SPIRAL; s++) nspv[s] = __builtin_nontemporal_load(pn + s);
        __builtin_amdgcn_sched_barrier(0);

        // 2) glds for tile tl+T into buf[p^1] (always 9, rows clamped).
        char* nbuf = mybuf + (p ^ 1) * BUFB;
#pragma unroll
        for (int s = 0; s < SPIRAL; s++) {
            const void* ga = (const char*)upb + (size_t)spv[s] * 64 + swz * 16;
            glds16(ga, nbuf + s * SLOTB);
        }
        __builtin_amdgcn_sched_barrier(0);

        // 3) wait: allow only the 9 youngest (tile tl+T's gathers) in flight.
        asm volatile("s_waitcnt vmcnt(9)" ::: "memory");
        __builtin_amdgcn_sched_barrier(0);

        // 4) compute tile tl from buf[p].
        char* cbuf = mybuf + p * BUFB;
        floatx4 acc0 = {0.f, 0.f, 0.f, 0.f};
        floatx4 acc1 = {0.f, 0.f, 0.f, 0.f};
#pragma unroll
        for (int s = 0; s < SPIRAL; s++) {
            short8_t g = *(const short8_t*)(cbuf + s * SLOTB + m * 64 + ((quad ^ fm) * 16));
            acc0 = __builtin_amdgcn_mfma_f32_16x16x32_bf16(w[2 * s + 0], g, acc0, 0, 0, 0);
            acc1 = __builtin_amdgcn_mfma_f32_16x16x32_bf16(w[2 * s + 1], g, acc1, 0, 0, 0);
        }

        int vr = tl * 64 + wave * 16 + m;
        if (vr < V_OUT) {
            float* op = dst + (size_t)vr * C_OUT;
            __builtin_nontemporal_store(acc0, (floatx4*)(op + quad * 4));
            __builtin_nontemporal_store(acc1, (floatx4*)(op + 16 + quad * 4));
        }

#pragma unroll
        for (int s = 0; s < SPIRAL; s++) spv[s] = nspv[s];
        p ^= 1;
    }
}

// Kernel 3: out = relu(out + p0 + bias). Pure streaming, nontemporal.
__global__ __launch_bounds__(256) void combine_kernel(
    const float* __restrict__ p0,
    const float* __restrict__ bias,
    float* __restrict__ out)
{
    const size_t total = (size_t)ROWS * (C_OUT / 4);   // 1.6M float4 units
    size_t idx = (size_t)blockIdx.x * 256 + threadIdx.x;
    size_t stride = (size_t)G3 * 256;
    for (size_t i = idx; i < total; i += stride) {
        floatx4 a = __builtin_nontemporal_load((const floatx4*)p0 + i);
        floatx4 c = __builtin_nontemporal_load((const floatx4*)out + i);
        floatx4 bb = *((const floatx4*)bias + (i & 7));
        floatx4 r = a + c + bb;
        r[0] = fmaxf(r[0], 0.f); r[1] = fmaxf(r[1], 0.f);
        r[2] = fmaxf(r[2], 0.f); r[3] = fmaxf(r[3], 0.f);
        __builtin_nontemporal_store(r, (floatx4*)out + i);
    }
}

extern "C" void kernel_launch(void* const* d_in, const int* in_sizes, int n_in,
                              void* d_out, int out_size, void* d_ws, size_t ws_size,
                              hipStream_t stream) {
    const float* x      = (const float*)d_in[0];
    const int*   spiral = (const int*)d_in[1];
    const int*   up_idx = (const int*)d_in[2];
    const float* up_val = (const float*)d_in[3];
    const float* weight = (const float*)d_in[4];
    const float* bias   = (const float*)d_in[5];
    float* out = (float*)d_out;

    // ws layout: planes (25.6 MB) | w_frag (36 KB) | p0 (25.6 MB) = 51.3 MB
    unsigned short* up_ws  = (unsigned short*)d_ws;
    unsigned short* w_frag = up_ws + (size_t)2 * B_ * V_OUT * 32;
    float* p0 = (float*)(w_frag + WFRAG_ELEMS);

    upsample_kernel<<<G1 + 1, 256, 0, stream>>>(x, up_idx, up_val, weight, up_ws, w_frag);
    gemm_half_kernel<<<G2, 256, 0, stream>>>(up_ws, spiral, w_frag, p0, out);
    combine_kernel<<<G3, 256, 0, stream>>>(p0, bias, out);
}

// Round 7
// 150.565 us; speedup vs baseline: 1.0977x; 1.0977x over previous
//
#include <hip/hip_runtime.h>
#include <hip/hip_bf16.h>

#define B_     4
#define V_IN   12500
#define V_OUT  50000
#define C_IN   64
#define C_OUT  32
#define SPIRAL 9
#define K_NNZ  3
#define ROWS   (B_ * V_OUT)       // 200000
#define KDIM   (SPIRAL * C_IN)    // 576
#define KSTEPS (KDIM / 32)        // 18 (16x16x32 MFMA)
#define WFRAG_ELEMS (KSTEPS * 2 * 64 * 8)  // 18432 bf16 = 36864 B

#define GROUPS_PER_B (V_OUT / 16) // 3125 16-row groups per batch (k1)
#define G1           2048         // k1 blocks (+1 W-prep); 256 per XCD
#define TILES_PER_B  782          // 781 full 64-row tiles + one 16-row tail (k2)
#define G2           512          // k2: 64 blocks per (b,ch) XCD; 2 blocks/CU (72KB LDS)
#define TSTEP        64           // tiles stride = blocks per partition
#define G3           2048         // combine blocks

#define SLOTB        1024         // bytes per gather slot (64 lanes * 16 B)
#define BUFB         (SPIRAL * SLOTB)      // 9216 B per wave per buffer

typedef __attribute__((ext_vector_type(8))) short short8_t;      // 8 bf16 (4 VGPRs)
typedef __attribute__((ext_vector_type(4))) float floatx4;       // 4 fp32 acc
typedef __attribute__((ext_vector_type(4))) unsigned short u16x4;

__device__ __forceinline__ unsigned short f32_to_bf16(float f) {
    unsigned int u = __float_as_uint(f);
    unsigned int r = u + 0x7fffu + ((u >> 16) & 1u);   // round-to-nearest-even
    return (unsigned short)(r >> 16);
}

// Async global->LDS, 16B per lane. LDS dest = base + lane*16 (linear, HW rule).
__device__ __forceinline__ void glds16(const void* g, void* l) {
    __builtin_amdgcn_global_load_lds(
        (const __attribute__((address_space(1))) unsigned int*)g,
        (__attribute__((address_space(3))) unsigned int*)l, 16, 0, 0);
}

// Kernel 1: up[b,v,c] = sum_k x[b,up_idx[v,k],c]*up_val[v,k] -> bf16,
// stored as TWO channel planes: plane[ch][b][v][32], ch = c>>5.
// Each plane per batch = 50000*64B = 3.2 MB -> fits one XCD's 4 MB L2 in k2.
// (R2 verified: gemm FETCH_SIZE 170 MB -> 19.8 MB with this layout.)
// Block G1: rearrange weight (576x32 fp32) into MFMA fragment order (bf16).
__global__ __launch_bounds__(256) void upsample_kernel(
    const float* __restrict__ x,
    const int* __restrict__ up_idx,
    const float* __restrict__ up_val,
    const float* __restrict__ weight,
    unsigned short* __restrict__ up_planes,
    unsigned short* __restrict__ w_frag)
{
    int tid = threadIdx.x;
    if (blockIdx.x == G1) {
        for (int idx = tid; idx < WFRAG_ELEMS; idx += 256) {
            int j     = idx & 7;
            int lane  = (idx >> 3) & 63;
            int ntile = (idx >> 9) & 1;
            int kstep = idx >> 10;
            int k = kstep * 32 + (lane >> 4) * 8 + j;
            int n = ntile * 16 + (lane & 15);
            w_frag[idx] = f32_to_bf16(weight[k * C_OUT + n]);
        }
        return;
    }
    int xcd = blockIdx.x & 7;
    int b   = xcd >> 1;                     // batch owned by this XCD pair
    int h   = xcd & 1;
    int j   = blockIdx.x >> 3;              // [0, 256)
    int lane16 = tid & 15;                  // 4 channels each
    int sub    = tid >> 4;                  // row within 16-row group
    int half   = lane16 >> 3;               // channel plane (c>=32)
    int c8     = lane16 & 7;                // 4-short chunk within plane row

    const float* xb = x + (size_t)b * V_IN * C_IN;
    unsigned short* plane = up_planes
        + ((size_t)(half * B_ + b)) * V_OUT * 32 + (size_t)c8 * 4;

    for (int gl = h + 2 * j; gl < GROUPS_PER_B; gl += 512) {
        int v = gl * 16 + sub;              // local row within batch b
        const int*   ui = up_idx + v * K_NNZ;
        const float* uv = up_val + v * K_NNZ;
        float a0 = 0.f, a1 = 0.f, a2 = 0.f, a3 = 0.f;
#pragma unroll
        for (int k = 0; k < K_NNZ; k++) {
            int u = __builtin_nontemporal_load(ui + k);
            float val = __builtin_nontemporal_load(uv + k);
            const float4* xp = (const float4*)(xb + (size_t)u * C_IN) + lane16;
            float4 xv = *xp;
            a0 += val * xv.x; a1 += val * xv.y; a2 += val * xv.z; a3 += val * xv.w;
        }
        u16x4 o;
        o[0] = f32_to_bf16(a0); o[1] = f32_to_bf16(a1);
        o[2] = f32_to_bf16(a2); o[3] = f32_to_bf16(a3);
        __builtin_nontemporal_store(o, (u16x4*)(plane + (size_t)v * 32));
    }
}

// Kernel 2: partial GEMM over one K-half. XCD xcd = b*2+ch.
// R7: double-buffered pipeline with DEPENDENCY-CARRIED waits (no drain):
//   per iter (computing tile t): spv<-nspv; glds(t+T -> buf^1) [compiler's
//   mandatory wait for the idx(t+T) values used as addresses retires
//   glds(t), since vmcnt retires IN-ORDER (m135) and glds(t) is older];
//   vmcnt(11) safety (9 new glds + 2 stores younger than glds(t));
//   idx(t+2T) prefetch (PLAIN cached loads -- R6's nt idx loads put ~900cy
//   HBM latency on the critical wait, the main R6 regression); compute(t);
//   nt store. Stores are never waited on: nothing drains vmcnt to 0.
__global__ __launch_bounds__(256, 2) void gemm_half_kernel(
    const unsigned short* __restrict__ up_planes,
    const int* __restrict__ spiral,
    const unsigned short* __restrict__ w_frag,
    float* __restrict__ p0,
    float* __restrict__ out)
{
    __shared__ unsigned short gbuf[4 * 2 * SPIRAL * 512];   // 4 waves * 2 bufs * 9 KB

    int tid  = threadIdx.x;
    int wave = tid >> 6;
    int lane = tid & 63;
    int m    = lane & 15;
    int quad = lane >> 4;
    int r    = lane >> 2;          // gather row within 16-row wave tile
    int q    = lane & 3;           // gather sector lane
    int swz  = q ^ ((r >> 1) & 3); // sector actually fetched by this lane
    int fm   = (m >> 1) & 3;       // read-side swizzle for row m

    int xcd = blockIdx.x & 7;
    int b   = xcd >> 1;
    int ch  = xcd & 1;
    int j   = blockIdx.x >> 3;              // [0, TSTEP)

    // W fragments for this half -> registers (loop-invariant, 72 VGPR).
    short8_t w[2 * SPIRAL];
#pragma unroll
    for (int f = 0; f < 2 * SPIRAL; f++) {
        int s  = f >> 1;
        int nt = f & 1;
        w[f] = *(const short8_t*)(w_frag + (((size_t)(2 * s + ch) * 2 + nt) * 64 + lane) * 8);
    }

    const unsigned short* upb = up_planes + ((size_t)(ch * B_ + b)) * V_OUT * 32;
    float* dst = (ch ? out : p0) + (size_t)b * V_OUT * C_OUT;
    char* mybuf = (char*)gbuf + (size_t)wave * 2 * BUFB;

    // ---- prologue: idx(j) -> glds(j -> buf0) -> idx(j+T) ----
    // Order matters: glds(j) must be OLDER than the idx(j+T) loads so the
    // first iteration's address-dependency wait retires glds(j).
    int spv[SPIRAL], nspv[SPIRAL];
    {
        int v0 = j * 64 + wave * 16 + r;
        v0 = v0 < V_OUT ? v0 : 0;
        const int* p = spiral + (size_t)v0 * SPIRAL;
#pragma unroll
        for (int s = 0; s < SPIRAL; s++) spv[s] = p[s];
        __builtin_amdgcn_sched_barrier(0);
#pragma unroll
        for (int s = 0; s < SPIRAL; s++) {
            const void* ga = (const char*)upb + (size_t)spv[s] * 64 + swz * 16;
            glds16(ga, mybuf + s * SLOTB);
        }
        __builtin_amdgcn_sched_barrier(0);
        int v1 = (j + TSTEP) * 64 + wave * 16 + r;
        v1 = v1 < V_OUT ? v1 : 0;
        const int* pn = spiral + (size_t)v1 * SPIRAL;
#pragma unroll
        for (int s = 0; s < SPIRAL; s++) nspv[s] = pn[s];
    }

    int p = 0;
    for (int tl = j; tl < TILES_PER_B; tl += TSTEP) {
        // 1) gathers for tile tl+T into buf[p^1]; addresses consume nspv ->
        //    compiler's vmcnt wait here retires glds(tl) (in-order).
#pragma unroll
        for (int s = 0; s < SPIRAL; s++) spv[s] = nspv[s];
        __builtin_amdgcn_sched_barrier(0);
        char* nbuf = mybuf + (p ^ 1) * BUFB;
#pragma unroll
        for (int s = 0; s < SPIRAL; s++) {
            const void* ga = (const char*)upb + (size_t)spv[s] * 64 + swz * 16;
            glds16(ga, nbuf + s * SLOTB);
        }
        // Safety: among ops younger than glds(tl) at this point (idx 9 +
        // stores 2 + new glds 9 = 20 of max 29 outstanding), <=11 in flight
        // guarantees the 9 oldest (= glds(tl)) retired.
        asm volatile("s_waitcnt vmcnt(11)" ::: "memory");
        __builtin_amdgcn_sched_barrier(0);

        // 2) idx prefetch for tile tl+2T (plain cached loads).
        int v2 = (tl + 2 * TSTEP) * 64 + wave * 16 + r;
        v2 = (v2 < V_OUT) ? v2 : 0;
        const int* pn = spiral + (size_t)v2 * SPIRAL;
#pragma unroll
        for (int s = 0; s < SPIRAL; s++) nspv[s] = pn[s];
        __builtin_amdgcn_sched_barrier(0);

        // 3) compute tile tl from buf[p].
        char* cbuf = mybuf + p * BUFB;
        floatx4 acc0 = {0.f, 0.f, 0.f, 0.f};
        floatx4 acc1 = {0.f, 0.f, 0.f, 0.f};
#pragma unroll
        for (int s = 0; s < SPIRAL; s++) {
            short8_t g = *(const short8_t*)(cbuf + s * SLOTB + m * 64 + ((quad ^ fm) * 16));
            acc0 = __builtin_amdgcn_mfma_f32_16x16x32_bf16(w[2 * s + 0], g, acc0, 0, 0, 0);
            acc1 = __builtin_amdgcn_mfma_f32_16x16x32_bf16(w[2 * s + 1], g, acc1, 0, 0, 0);
        }

        int vr = tl * 64 + wave * 16 + m;
        if (vr < V_OUT) {
            float* op = dst + (size_t)vr * C_OUT;
            __builtin_nontemporal_store(acc0, (floatx4*)(op + quad * 4));
            __builtin_nontemporal_store(acc1, (floatx4*)(op + 16 + quad * 4));
        }

        p ^= 1;
    }
}

// Kernel 3: out = relu(out + p0 + bias). Pure streaming, nontemporal.
__global__ __launch_bounds__(256) void combine_kernel(
    const float* __restrict__ p0,
    const float* __restrict__ bias,
    float* __restrict__ out)
{
    const size_t total = (size_t)ROWS * (C_OUT / 4);   // 1.6M float4 units
    size_t idx = (size_t)blockIdx.x * 256 + threadIdx.x;
    size_t stride = (size_t)G3 * 256;
    for (size_t i = idx; i < total; i += stride) {
        floatx4 a = __builtin_nontemporal_load((const floatx4*)p0 + i);
        floatx4 c = __builtin_nontemporal_load((const floatx4*)out + i);
        floatx4 bb = *((const floatx4*)bias + (i & 7));
        floatx4 r = a + c + bb;
        r[0] = fmaxf(r[0], 0.f); r[1] = fmaxf(r[1], 0.f);
        r[2] = fmaxf(r[2], 0.f); r[3] = fmaxf(r[3], 0.f);
        __builtin_nontemporal_store(r, (floatx4*)out + i);
    }
}

extern "C" void kernel_launch(void* const* d_in, const int* in_sizes, int n_in,
                              void* d_out, int out_size, void* d_ws, size_t ws_size,
                              hipStream_t stream) {
    const float* x      = (const float*)d_in[0];
    const int*   spiral = (const int*)d_in[1];
    const int*   up_idx = (const int*)d_in[2];
    const float* up_val = (const float*)d_in[3];
    const float* weight = (const float*)d_in[4];
    const float* bias   = (const float*)d_in[5];
    float* out = (float*)d_out;

    // ws layout: planes (25.6 MB) | w_frag (36 KB) | p0 (25.6 MB) = 51.3 MB
    unsigned short* up_ws  = (unsigned short*)d_ws;
    unsigned short* w_frag = up_ws + (size_t)2 * B_ * V_OUT * 32;
    float* p0 = (float*)(w_frag + WFRAG_ELEMS);

    upsample_kernel<<<G1 + 1, 256, 0, stream>>>(x, up_idx, up_val, weight, up_ws, w_frag);
    gemm_half_kernel<<<G2, 256, 0, stream>>>(up_ws, spiral, w_frag, p0, out);
    combine_kernel<<<G3, 256, 0, stream>>>(p0, bias, out);
}

// Round 8
// 141.338 us; speedup vs baseline: 1.1694x; 1.0653x over previous
//
#include <hip/hip_runtime.h>
#include <hip/hip_bf16.h>

#define B_     4
#define V_IN   12500
#define V_OUT  50000
#define C_IN   64
#define C_OUT  32
#define SPIRAL 9
#define K_NNZ  3
#define ROWS   (B_ * V_OUT)       // 200000
#define KDIM   (SPIRAL * C_IN)    // 576
#define KSTEPS (KDIM / 32)        // 18 (16x16x32 MFMA)
#define WFRAG_ELEMS (KSTEPS * 2 * 64 * 8)  // 18432 bf16 = 36864 B

#define GROUPS_PER_B (V_OUT / 16) // 3125 16-row groups per batch (k1)
#define G1           2048         // k1 blocks (+1 W-prep); 256 per XCD
#define TILES_PER_B  782          // 781 full 64-row tiles + one 16-row tail (k2)
#define G2           1024         // k2: 128 blocks per (b,ch) XCD; 4 blocks/CU (36KB LDS)
#define TSTEP        128          // tiles stride = blocks per partition
#define G3           2048         // combine blocks

#define SLOTB        1024         // bytes per gather slot (64 lanes * 16 B)
#define BUFB         (SPIRAL * SLOTB)      // 9216 B per wave (single buffer)

typedef __attribute__((ext_vector_type(8))) short short8_t;      // 8 bf16 (4 VGPRs)
typedef __attribute__((ext_vector_type(4))) float floatx4;       // 4 fp32 acc

__device__ __forceinline__ unsigned short f32_to_bf16(float f) {
    unsigned int u = __float_as_uint(f);
    unsigned int r = u + 0x7fffu + ((u >> 16) & 1u);   // round-to-nearest-even
    return (unsigned short)(r >> 16);
}

// Async global->LDS, 16B per lane. LDS dest = base + lane*16 (linear, HW rule).
__device__ __forceinline__ void glds16(const void* g, void* l) {
    __builtin_amdgcn_global_load_lds(
        (const __attribute__((address_space(1))) unsigned int*)g,
        (__attribute__((address_space(3))) unsigned int*)l, 16, 0, 0);
}

// Kernel 1: up[b,v,c] = sum_k x[b,up_idx[v,k],c]*up_val[v,k] -> bf16 planes
// plane[ch][b][v][32], ch = c>>5. R8: XCD 2b+h produces plane h of batch b
// ENTIRELY (same XCD that k2 reads it on -> dirty-L2 locality across the
// kernel boundary; cached stores). Each XCD reads only the h-half line of
// each gathered x row -> 1.6 MB L2 footprint. idx/val loads are PLAIN
// cached (R6 lesson: nt loads = exposed ~900cy HBM latency).
// Block G1: rearrange weight (576x32 fp32) into MFMA fragment order (bf16):
//   w_frag[((kstep*2+ntile)*64+lane)*8+j] = W[kstep*32+(lane>>4)*8+j][ntile*16+(lane&15)]
__global__ __launch_bounds__(256) void upsample_kernel(
    const float* __restrict__ x,
    const int* __restrict__ up_idx,
    const float* __restrict__ up_val,
    const float* __restrict__ weight,
    unsigned short* __restrict__ up_planes,
    unsigned short* __restrict__ w_frag)
{
    int tid = threadIdx.x;
    if (blockIdx.x == G1) {
        for (int idx = tid; idx < WFRAG_ELEMS; idx += 256) {
            int j     = idx & 7;
            int lane  = (idx >> 3) & 63;
            int ntile = (idx >> 9) & 1;
            int kstep = idx >> 10;
            int k = kstep * 32 + (lane >> 4) * 8 + j;
            int n = ntile * 16 + (lane & 15);
            w_frag[idx] = f32_to_bf16(weight[k * C_OUT + n]);
        }
        return;
    }
    int xcd = blockIdx.x & 7;
    int b   = xcd >> 1;                     // batch owned by this XCD
    int h   = xcd & 1;                      // channel plane owned by this XCD
    int j   = blockIdx.x >> 3;              // [0, 256)
    int lane16 = tid & 15;                  // 2 channels each (ushort2 out)
    int sub    = tid >> 4;                  // row within 16-row group

    const float* xb = x + (size_t)b * V_IN * C_IN + h * 32;  // half-row base
    unsigned short* plane = up_planes + ((size_t)(h * B_ + b)) * V_OUT * 32;

    for (int gl = j; gl < GROUPS_PER_B; gl += 256) {
        int v = gl * 16 + sub;              // local row within batch b
        const int*   ui = up_idx + v * K_NNZ;
        const float* uv = up_val + v * K_NNZ;
        float a0 = 0.f, a1 = 0.f;
#pragma unroll
        for (int k = 0; k < K_NNZ; k++) {
            int u = ui[k];
            float val = uv[k];
            const float2* xp = (const float2*)(xb + (size_t)u * C_IN) + lane16;
            float2 xv = *xp;
            a0 += val * xv.x; a1 += val * xv.y;
        }
        ushort2 o;
        o.x = f32_to_bf16(a0); o.y = f32_to_bf16(a1);
        *((ushort2*)(plane + (size_t)v * 32) + lane16) = o;   // cached: k2 reads on this XCD
    }
}

// Kernel 2: partial GEMM over one K-half. XCD xcd = b*2+ch (same mapping as
// k1's writer). R8: single 36KB buffer (4 blocks/CU, 32 waves/CU) + counted
// vmcnt(5) pipeline:
//   per-iter VMEM ops (exact): 9 glds + 3 idx loads (int4+int4+int, 9
//   contiguous ints can't codegen to <3) + 2 float4 nt stores (64B apart,
//   unmergeable). Body order: compute(t) -> glds(t+1) -> idx(t+2) ->
//   store(t). Loop-top vmcnt(5) leaves only the 5 youngest (idx+stores)
//   in flight -> glds(t) retired (issued a full iter earlier: wait ~free),
//   stores get a full iteration to ack (R5's vmcnt(0) drain waited on nt
//   store acks every tile -- in-order retirement). Over-wait safe,
//   under-wait impossible (younger ops >= 5 by construction).
__global__ __launch_bounds__(256, 4) void gemm_half_kernel(
    const unsigned short* __restrict__ up_planes,
    const int* __restrict__ spiral,
    const unsigned short* __restrict__ w_frag,
    float* __restrict__ p0,
    float* __restrict__ out)
{
    __shared__ unsigned short gbuf[4 * SPIRAL * 512];   // 4 waves * 9 KB

    int tid  = threadIdx.x;
    int wave = tid >> 6;
    int lane = tid & 63;
    int m    = lane & 15;
    int quad = lane >> 4;
    int r    = lane >> 2;          // gather row within 16-row wave tile
    int q    = lane & 3;           // gather sector lane
    int swz  = q ^ ((r >> 1) & 3); // sector actually fetched by this lane
    int fm   = (m >> 1) & 3;       // read-side swizzle for row m

    int xcd = blockIdx.x & 7;
    int b   = xcd >> 1;
    int ch  = xcd & 1;
    int j   = blockIdx.x >> 3;              // [0, TSTEP)

    // W fragments for this half -> registers (loop-invariant, 72 VGPR).
    short8_t w[2 * SPIRAL];
#pragma unroll
    for (int f = 0; f < 2 * SPIRAL; f++) {
        int s  = f >> 1;
        int nt = f & 1;
        w[f] = *(const short8_t*)(w_frag + (((size_t)(2 * s + ch) * 2 + nt) * 64 + lane) * 8);
    }

    const unsigned short* upb = up_planes + ((size_t)(ch * B_ + b)) * V_OUT * 32;
    float* dst = (ch ? out : p0) + (size_t)b * V_OUT * C_OUT;
    char* mybuf = (char*)gbuf + (size_t)wave * BUFB;

    int nspv[SPIRAL];
    // ---- prologue: idx(t0) -> glds(t0) -> vmcnt(0) -> idx(t1) ----
    {
        int v0 = j * 64 + wave * 16 + r;
        v0 = v0 < V_OUT ? v0 : 0;
        const int* p = spiral + (size_t)v0 * SPIRAL;
        int4 ia = *(const int4*)p;
        int4 ib = *(const int4*)(p + 4);
        int  ic = p[8];
        nspv[0]=ia.x; nspv[1]=ia.y; nspv[2]=ia.z; nspv[3]=ia.w;
        nspv[4]=ib.x; nspv[5]=ib.y; nspv[6]=ib.z; nspv[7]=ib.w; nspv[8]=ic;
        __builtin_amdgcn_sched_barrier(0);
#pragma unroll
        for (int s = 0; s < SPIRAL; s++) {
            const void* ga = (const char*)upb + (size_t)nspv[s] * 64 + swz * 16;
            glds16(ga, mybuf + s * SLOTB);
        }
        asm volatile("s_waitcnt vmcnt(0)" ::: "memory");
        __builtin_amdgcn_sched_barrier(0);
        int v1 = (j + TSTEP) * 64 + wave * 16 + r;
        v1 = v1 < V_OUT ? v1 : 0;
        const int* pn = spiral + (size_t)v1 * SPIRAL;
        int4 ja = *(const int4*)pn;
        int4 jb = *(const int4*)(pn + 4);
        int  jc = pn[8];
        nspv[0]=ja.x; nspv[1]=ja.y; nspv[2]=ja.z; nspv[3]=ja.w;
        nspv[4]=jb.x; nspv[5]=jb.y; nspv[6]=jb.z; nspv[7]=jb.w; nspv[8]=jc;
    }

    for (int tl = j; tl < TILES_PER_B; tl += TSTEP) {
        // 0) wait: only the 5 youngest VMEM ops (idx(t+1)=3, store(t-1)=2)
        //    may remain in flight -> glds(t) complete.
        asm volatile("s_waitcnt vmcnt(5)" ::: "memory");
        __builtin_amdgcn_sched_barrier(0);

        // 1) compute tile t from the single buffer.
        floatx4 acc0 = {0.f, 0.f, 0.f, 0.f};
        floatx4 acc1 = {0.f, 0.f, 0.f, 0.f};
#pragma unroll
        for (int s = 0; s < SPIRAL; s++) {
            short8_t g = *(const short8_t*)(mybuf + s * SLOTB + m * 64 + ((quad ^ fm) * 16));
            acc0 = __builtin_amdgcn_mfma_f32_16x16x32_bf16(w[2 * s + 0], g, acc0, 0, 0, 0);
            acc1 = __builtin_amdgcn_mfma_f32_16x16x32_bf16(w[2 * s + 1], g, acc1, 0, 0, 0);
        }
        __builtin_amdgcn_sched_barrier(0);   // ds_reads issued before glds below

        int tln = tl + TSTEP;
        if (tln < TILES_PER_B) {             // block-uniform
            // 2) glds(t+1) into the same buffer (addresses = nspv, loaded
            //    a full iteration ago -> compiler's idx-wait is free; LDS
            //    overwrite is safe: ds_reads above issued before these,
            //    data returns >=250cy after issue).
#pragma unroll
            for (int s = 0; s < SPIRAL; s++) {
                const void* ga = (const char*)upb + (size_t)nspv[s] * 64 + swz * 16;
                glds16(ga, mybuf + s * SLOTB);
            }
            __builtin_amdgcn_sched_barrier(0);
            // 3) idx(t+2) prefetch (plain cached; 3 VMEM ops).
            int v2 = (tln + TSTEP) * 64 + wave * 16 + r;
            v2 = (v2 < V_OUT) ? v2 : 0;
            const int* pn = spiral + (size_t)v2 * SPIRAL;
            int4 ja = *(const int4*)pn;
            int4 jb = *(const int4*)(pn + 4);
            int  jc = pn[8];
            nspv[0]=ja.x; nspv[1]=ja.y; nspv[2]=ja.z; nspv[3]=ja.w;
            nspv[4]=jb.x; nspv[5]=jb.y; nspv[6]=jb.z; nspv[7]=jb.w; nspv[8]=jc;
            __builtin_amdgcn_sched_barrier(0);
        }

        // 4) store(t) -- youngest VMEM ops; never explicitly waited.
        int vr = tl * 64 + wave * 16 + m;
        if (vr < V_OUT) {
            float* op = dst + (size_t)vr * C_OUT;
            __builtin_nontemporal_store(acc0, (floatx4*)(op + quad * 4));
            __builtin_nontemporal_store(acc1, (floatx4*)(op + 16 + quad * 4));
        }
    }
}

// Kernel 3: out = relu(out + p0 + bias). Pure streaming, nontemporal.
__global__ __launch_bounds__(256) void combine_kernel(
    const float* __restrict__ p0,
    const float* __restrict__ bias,
    float* __restrict__ out)
{
    const size_t total = (size_t)ROWS * (C_OUT / 4);   // 1.6M float4 units
    size_t idx = (size_t)blockIdx.x * 256 + threadIdx.x;
    size_t stride = (size_t)G3 * 256;
    for (size_t i = idx; i < total; i += stride) {
        floatx4 a = __builtin_nontemporal_load((const floatx4*)p0 + i);
        floatx4 c = __builtin_nontemporal_load((const floatx4*)out + i);
        floatx4 bb = *((const floatx4*)bias + (i & 7));
        floatx4 r = a + c + bb;
        r[0] = fmaxf(r[0], 0.f); r[1] = fmaxf(r[1], 0.f);
        r[2] = fmaxf(r[2], 0.f); r[3] = fmaxf(r[3], 0.f);
        __builtin_nontemporal_store(r, (floatx4*)out + i);
    }
}

extern "C" void kernel_launch(void* const* d_in, const int* in_sizes, int n_in,
                              void* d_out, int out_size, void* d_ws, size_t ws_size,
                              hipStream_t stream) {
    const float* x      = (const float*)d_in[0];
    const int*   spiral = (const int*)d_in[1];
    const int*   up_idx = (const int*)d_in[2];
    const float* up_val = (const float*)d_in[3];
    const float* weight = (const float*)d_in[4];
    const float* bias   = (const float*)d_in[5];
    float* out = (float*)d_out;

    // ws layout: planes (25.6 MB) | w_frag (36 KB) | p0 (25.6 MB) = 51.3 MB
    unsigned short* up_ws  = (unsigned short*)d_ws;
    unsigned short* w_frag = up_ws + (size_t)2 * B_ * V_OUT * 32;
    float* p0 = (float*)(w_frag + WFRAG_ELEMS);

    upsample_kernel<<<G1 + 1, 256, 0, stream>>>(x, up_idx, up_val, weight, up_ws, w_frag);
    gemm_half_kernel<<<G2, 256, 0, stream>>>(up_ws, spiral, w_frag, p0, out);
    combine_kernel<<<G3, 256, 0, stream>>>(p0, bias, out);
}